// Round 1
// baseline (424.674 us; speedup 1.0000x reference)
//
#include <hip/hip_runtime.h>

// MoEALU add + xor over one-hot byte-distribution encodings.
//
// Inputs are exact one-hot [B,4,256] float32 encodings; with SCALE=100 every
// softmax in the reference returns a distribution whose peak is exactly 1.0f
// in float32 and whose off-peak entries are exp(-100) ~ 3.8e-44 (denormal).
// So the whole soft-ALU collapses to exact integer add/xor and exact one-hot
// outputs. Memory-bound: 256 MiB read + 256 MiB write => ~85 us floor.

__global__ __launch_bounds__(256) void moe_alu_kernel(
    const float* __restrict__ A,
    const float* __restrict__ Bmat,
    float* __restrict__ out,
    int B)
{
    const int bid  = blockIdx.x;          // batch element
    const int t    = threadIdx.x;         // 0..255
    const int wave = t >> 6;              // 0..3 = byte index (little-endian)
    const int lane = t & 63;

    // Each batch element is 4*256 = 1024 floats = 256 float4's.
    const float4* a4 = reinterpret_cast<const float4*>(A)    + (size_t)bid * 256;
    const float4* b4 = reinterpret_cast<const float4*>(Bmat) + (size_t)bid * 256;

    // Thread t covers floats [4t, 4t+3]; wave w covers byte-row w (256 floats).
    const float4 av = a4[t];
    const float4 bv = b4[t];

    const int base = lane * 4;            // position within the 256-wide row
    int ai = 0, bi = 0;
    if (av.x > 0.5f) ai = base + 0;
    if (av.y > 0.5f) ai = base + 1;
    if (av.z > 0.5f) ai = base + 2;
    if (av.w > 0.5f) ai = base + 3;
    if (bv.x > 0.5f) bi = base + 0;
    if (bv.y > 0.5f) bi = base + 1;
    if (bv.z > 0.5f) bi = base + 2;
    if (bv.w > 0.5f) bi = base + 3;

    // 64-lane max-reduce: exactly one lane holds the hot index (others 0;
    // index 0 is the all-zero case, which max handles correctly).
    #pragma unroll
    for (int off = 32; off > 0; off >>= 1) {
        ai = max(ai, __shfl_xor(ai, off, 64));
        bi = max(bi, __shfl_xor(bi, off, 64));
    }

    __shared__ unsigned sA[4], sB[4];
    if (lane == 0) { sA[wave] = (unsigned)ai; sB[wave] = (unsigned)bi; }
    __syncthreads();

    const unsigned a32 = sA[0] | (sA[1] << 8) | (sA[2] << 16) | (sA[3] << 24);
    const unsigned b32 = sB[0] | (sB[1] << 8) | (sB[2] << 16) | (sB[3] << 24);
    const unsigned s32 = a32 + b32;   // full carry chain == reference's soft carry chain
    const unsigned x32 = a32 ^ b32;

    const unsigned sb  = (s32 >> (8 * wave)) & 255u;  // result byte for this wave's row
    const unsigned xb  = (x32 >> (8 * wave)) & 255u;
    const unsigned pos = (unsigned)base;

    float4 va, vx;
    va.x = (sb == pos + 0u) ? 1.0f : 0.0f;
    va.y = (sb == pos + 1u) ? 1.0f : 0.0f;
    va.z = (sb == pos + 2u) ? 1.0f : 0.0f;
    va.w = (sb == pos + 3u) ? 1.0f : 0.0f;
    vx.x = (xb == pos + 0u) ? 1.0f : 0.0f;
    vx.y = (xb == pos + 1u) ? 1.0f : 0.0f;
    vx.z = (xb == pos + 2u) ? 1.0f : 0.0f;
    vx.w = (xb == pos + 3u) ? 1.0f : 0.0f;

    // Output layout [2, B, 4, 256]: add block then xor block.
    float4* oadd = reinterpret_cast<float4*>(out) + (size_t)bid * 256;
    float4* oxor = reinterpret_cast<float4*>(out) + ((size_t)B + (size_t)bid) * 256;
    oadd[t] = va;
    oxor[t] = vx;
}

extern "C" void kernel_launch(void* const* d_in, const int* in_sizes, int n_in,
                              void* d_out, int out_size, void* d_ws, size_t ws_size,
                              hipStream_t stream) {
    const float* a = (const float*)d_in[0];
    const float* b = (const float*)d_in[1];
    float* out = (float*)d_out;
    const int B = in_sizes[0] / 1024;   // [B,4,256]

    moe_alu_kernel<<<B, 256, 0, stream>>>(a, b, out, B);
}